// Round 1
// 445.148 us; speedup vs baseline: 1.0020x; 1.0020x over previous
//
#include <hip/hip_runtime.h>
#include <hip/hip_bf16.h>

// Problem constants (fixed by reference): N=262144 rows, D=64, K=512 codes.
#define N_ROWS 262144
#define DIM 64
#define KC 512

// d_out layout — FLOAT32 (confirmed R2: outputs 0/1 passed with this layout):
//   out[0]                      = loss
//   out[1 .. 1+N*D)             = quantized [N,64] row-major
//   out[1+N*D .. 1+N*D+N)       = float(encoding_indices)
//
// Indices must match np.argmin of the reference's FLOAT32 distance array
// bit-for-bit. We replicate numpy's f32 numerics exactly:
//   x_sq, e_sq : numpy pairwise sum, n=64 => 8-accumulator striped scheme,
//                squares rounded separately (no FMA)
//   dot        : OpenBLAS sgemm microkernel = sequential fused-FMA chain
//   d          : fl( fl(x_sq + e_sq_k) - 2*dot_k ), contraction off
//   argmin     : strict <, first-min-wins (k ascending)

// numpy pairwise sum of squares for n=64 (scalar path, PW_BLOCKSIZE=128):
//   r[j] = sum_{i ≡ j mod 8} fl(a_i*a_i), sequential in i;
//   res  = ((r0+r1)+(r2+r3)) + ((r4+r5)+(r6+r7))
__device__ __forceinline__ float np_sumsq64(const float* a) {
#pragma clang fp contract(off)
    float r[8];
#pragma unroll
    for (int j = 0; j < 8; ++j) r[j] = a[j] * a[j];
#pragma unroll
    for (int i = 8; i < 64; i += 8)
#pragma unroll
        for (int j = 0; j < 8; ++j) r[j] = r[j] + a[i + j] * a[i + j];
    return ((r[0] + r[1]) + (r[2] + r[3])) + ((r[4] + r[5]) + (r[6] + r[7]));
}

// ---- kernel 1: e_sq_k with numpy bit-exact summation ----
__global__ void esq_kernel(const float* __restrict__ cb, float* __restrict__ esq) {
    int k = blockIdx.x * blockDim.x + threadIdx.x;
    if (k < KC) esq[k] = np_sumsq64(cb + k * DIM);
}

// ---- kernel 2: main VQ — one thread per row ----
// R(prev): VGPR_Count=40 < 64 proved the row was NOT register-resident; the
// compiler re-fetched it from L1/L2 every k iteration (~32 GB of redundant
// reads ≈ aggregate L1 ceiling over the measured 377 µs). Fix: asm-pin the
// 64 row values into VGPRs, allow up to 128 VGPRs, and unroll k by 4 to get
// four independent dependent-FMA chains (covers the 4-cycle FMA latency).
__global__ __launch_bounds__(256, 4) void vq_kernel(
    const float* __restrict__ x, const float* __restrict__ cb,
    const float* __restrict__ esq, float* __restrict__ out,
    float* __restrict__ loss_acc)
{
    const int row = blockIdx.x * 256 + threadIdx.x;
    if (row >= N_ROWS) return;

    // Row into 64 VGPRs (16x float4, 256B-aligned).
    float xr[DIM];
    const float4* xv = reinterpret_cast<const float4*>(x + (size_t)row * DIM);
#pragma unroll
    for (int j = 0; j < DIM / 4; ++j) {
        float4 v = xv[j];
        xr[4 * j + 0] = v.x; xr[4 * j + 1] = v.y;
        xr[4 * j + 2] = v.z; xr[4 * j + 3] = v.w;
    }
    // Pin each row element to a VGPR: the empty asm "modifies" the value, so
    // the compiler cannot sink/rematerialize the global loads into the k-loop
    // or fold them to scratch. This is the whole fix.
#pragma unroll
    for (int j = 0; j < DIM; ++j) asm volatile("" : "+v"(xr[j]));

    // numpy-exact ||x||^2 (f32 bits matter: they set where fl(x_sq+e_sq)
    // lands relative to rounding boundaries).
    const float xsq = np_sumsq64(xr);

    // Replicated reference distance, argmin first-min-wins, k ascending.
    float best = 3.4e38f;
    int bidx = 0;
#pragma unroll 1
    for (int k = 0; k < KC; k += 4) {
        const float* e = cb + (size_t)k * DIM;   // wave-uniform -> s_load
        // sgemm-style dots: each a single-accumulator sequential fused-FMA
        // chain (bit-identical to the reference's OpenBLAS microkernel);
        // the four chains are mutually independent => ILP for the scheduler.
        float dot0 = 0.f, dot1 = 0.f, dot2 = 0.f, dot3 = 0.f;
#pragma unroll
        for (int j = 0; j < DIM; ++j) {
            dot0 = fmaf(xr[j], e[j            ], dot0);
            dot1 = fmaf(xr[j], e[DIM     + j  ], dot1);
            dot2 = fmaf(xr[j], e[2 * DIM + j  ], dot2);
            dot3 = fmaf(xr[j], e[3 * DIM + j  ], dot3);
        }
        float d0, d1, d2, d3;
        {
#pragma clang fp contract(off)
            d0 = (xsq + esq[k + 0]) - 2.0f * dot0;  // 2*dot exact; each op rounds
            d1 = (xsq + esq[k + 1]) - 2.0f * dot1;
            d2 = (xsq + esq[k + 2]) - 2.0f * dot2;
            d3 = (xsq + esq[k + 3]) - 2.0f * dot3;
        }
        // strict <, processed in ascending k: first-min-wins preserved.
        if (d0 < best) { best = d0; bidx = k + 0; }
        if (d1 < best) { best = d1; bidx = k + 1; }
        if (d2 < best) { best = d2; bidx = k + 2; }
        if (d3 < best) { best = d3; bidx = k + 3; }
    }

    // quantized = codebook[bidx]
    const float* eb = cb + (size_t)bidx * DIM;
    float* q = out + 1 + (size_t)row * DIM;
#pragma unroll
    for (int j = 0; j < DIM; ++j) q[j] = eb[j];

    out[1 + (size_t)N_ROWS * DIM + row] = (float)bidx;

    // loss contribution: ||x - e||^2 = d_best (noise ~1e-5, threshold ~2%)
    float lrow = best;
#pragma unroll
    for (int off = 32; off > 0; off >>= 1) lrow += __shfl_down(lrow, off, 64);
    if ((threadIdx.x & 63) == 0) atomicAdd(loss_acc, lrow);
}

// ---- kernel 3: finalize loss ----
__global__ void fin_kernel(const float* __restrict__ loss_acc,
                           float* __restrict__ out) {
    if (threadIdx.x == 0) {
        float mean_sq = (*loss_acc) / (float)((size_t)N_ROWS * DIM);
        out[0] = 1.25f * mean_sq;  // q_loss + COMMITMENT_COST * e_loss
    }
}

extern "C" void kernel_launch(void* const* d_in, const int* in_sizes, int n_in,
                              void* d_out, int out_size, void* d_ws, size_t ws_size,
                              hipStream_t stream) {
    const float* x  = (const float*)d_in[0];
    const float* cb = (const float*)d_in[1];
    float* out = (float*)d_out;

    float* loss_acc = (float*)d_ws;                 // 4 B accumulator
    float* esq      = (float*)((char*)d_ws + 256);  // 512 floats

    hipMemsetAsync(d_ws, 0, 4, stream);             // zero loss accumulator
    esq_kernel<<<2, 256, 0, stream>>>(cb, esq);
    vq_kernel<<<N_ROWS / 256, 256, 0, stream>>>(x, cb, esq, out, loss_acc);
    fin_kernel<<<1, 64, 0, stream>>>(loss_acc, out);
}

// Round 3
// 430.473 us; speedup vs baseline: 1.0361x; 1.0341x over previous
//
#include <hip/hip_runtime.h>
#include <hip/hip_bf16.h>

// Problem constants (fixed by reference): N=262144 rows, D=64, K=512 codes.
#define N_ROWS 262144
#define DIM 64
#define KC 512

// d_out layout — FLOAT32 (confirmed R2: outputs 0/1 passed with this layout):
//   out[0]                      = loss
//   out[1 .. 1+N*D)             = quantized [N,64] row-major
//   out[1+N*D .. 1+N*D+N)       = float(encoding_indices)
//
// Indices must match np.argmin of the reference's FLOAT32 distance array
// bit-for-bit. We replicate numpy's f32 numerics exactly:
//   x_sq, e_sq : numpy pairwise sum, n=64 => 8-accumulator striped scheme,
//                squares rounded separately (no FMA)
//   dot        : OpenBLAS sgemm microkernel = sequential fused-FMA chain
//   d          : fl( fl(x_sq + e_sq_k) - 2*dot_k ), contraction off
//   argmin     : strict <, first-min-wins (k ascending)
//
// R1 post-mortem: VGPR_Count stayed 40 => row NOT register-resident; the
// allocator spilled xr because the k-body's hoisted e-tiles (4 rows = 256
// floats under the x4 unroll) blew the 128-VGPR cap of launch_bounds(.,4).
// R2 fix (re-submitted R3; R2 bench was an infra failure, no signal):
// cap 256 VGPRs (launch_bounds(256,2)), k-unroll x2 only (two independent
// FMA chains cover the 4-cyc FMA latency at 2-cyc issue), and a
// wave-cooperative coalesced epilogue.

// numpy pairwise sum of squares for n=64 (scalar path, PW_BLOCKSIZE=128):
//   r[j] = sum_{i ≡ j mod 8} fl(a_i*a_i), sequential in i;
//   res  = ((r0+r1)+(r2+r3)) + ((r4+r5)+(r6+r7))
__device__ __forceinline__ float np_sumsq64(const float* a) {
#pragma clang fp contract(off)
    float r[8];
#pragma unroll
    for (int j = 0; j < 8; ++j) r[j] = a[j] * a[j];
#pragma unroll
    for (int i = 8; i < 64; i += 8)
#pragma unroll
        for (int j = 0; j < 8; ++j) r[j] = r[j] + a[i + j] * a[i + j];
    return ((r[0] + r[1]) + (r[2] + r[3])) + ((r[4] + r[5]) + (r[6] + r[7]));
}

// ---- kernel 1: e_sq_k with numpy bit-exact summation ----
__global__ void esq_kernel(const float* __restrict__ cb, float* __restrict__ esq) {
    int k = blockIdx.x * blockDim.x + threadIdx.x;
    if (k < KC) esq[k] = np_sumsq64(cb + k * DIM);
}

// ---- kernel 2: main VQ — one thread per row ----
__global__ __launch_bounds__(256, 2) void vq_kernel(
    const float* __restrict__ x, const float* __restrict__ cb,
    const float* __restrict__ esq, float* __restrict__ out,
    float* __restrict__ loss_acc)
{
    const int row  = blockIdx.x * 256 + threadIdx.x;
    const int lane = threadIdx.x & 63;

    // Row into 64 VGPRs (16x float4, 256B-aligned).
    float xr[DIM];
    const float4* xv = reinterpret_cast<const float4*>(x + (size_t)row * DIM);
#pragma unroll
    for (int j = 0; j < DIM / 4; ++j) {
        float4 v = xv[j];
        xr[4 * j + 0] = v.x; xr[4 * j + 1] = v.y;
        xr[4 * j + 2] = v.z; xr[4 * j + 3] = v.w;
    }
    // Pin each row element to a VGPR (blocks load-remat into the k-loop).
    // With the 256-VGPR cap this time, the allocator has no reason to spill.
#pragma unroll
    for (int j = 0; j < DIM; ++j) asm volatile("" : "+v"(xr[j]));

    // numpy-exact ||x||^2 (f32 bits matter: they set where fl(x_sq+e_sq)
    // lands relative to rounding boundaries).
    const float xsq = np_sumsq64(xr);

    // Replicated reference distance, argmin first-min-wins, k ascending.
    // k-unroll x2: two independent single-accumulator sequential fused-FMA
    // chains (each bit-identical to the reference's OpenBLAS microkernel);
    // 2 chains x 4-cyc FMA latency / 2-cyc issue => VALU saturated even at
    // 2 waves/SIMD.
    float best = 3.4e38f;
    int bidx = 0;
#pragma unroll 1
    for (int k = 0; k < KC; k += 2) {
        const float* e = cb + (size_t)k * DIM;   // wave-uniform address
        float dot0 = 0.f, dot1 = 0.f;
#pragma unroll
        for (int j = 0; j < DIM; ++j) {
            dot0 = fmaf(xr[j], e[j      ], dot0);
            dot1 = fmaf(xr[j], e[DIM + j], dot1);
        }
        float d0, d1;
        {
#pragma clang fp contract(off)
            d0 = (xsq + esq[k + 0]) - 2.0f * dot0;  // 2*dot exact; each op rounds
            d1 = (xsq + esq[k + 1]) - 2.0f * dot1;
        }
        // strict <, ascending k: first-min-wins preserved.
        if (d0 < best) { best = d0; bidx = k + 0; }
        if (d1 < best) { best = d1; bidx = k + 1; }
    }

    // ---- wave-cooperative coalesced epilogue ----
    // R1 showed WRITE_SIZE ~310MB vs ~68MB real output: the per-thread
    // 64x dword stores at 256B lane stride never merged. Instead: broadcast
    // each lane's bidx, then the whole wave writes that row contiguously
    // (lane j writes element j => one coalesced 256B store per row).
    const size_t wave_row0 = (size_t)row - lane;
#pragma unroll 4
    for (int l = 0; l < 64; ++l) {
        const int idx = __shfl(bidx, l, 64);
        const float v = cb[(size_t)idx * DIM + lane];          // coalesced 256B read (L2-hot)
        out[1 + (wave_row0 + l) * DIM + lane] = v;             // coalesced 256B write
    }

    out[1 + (size_t)N_ROWS * DIM + row] = (float)bidx;         // coalesced

    // loss contribution: ||x - e||^2 = d_best (noise ~1e-5, threshold ~2%)
    float lrow = best;
#pragma unroll
    for (int off = 32; off > 0; off >>= 1) lrow += __shfl_down(lrow, off, 64);
    if (lane == 0) atomicAdd(loss_acc, lrow);
}

// ---- kernel 3: finalize loss ----
__global__ void fin_kernel(const float* __restrict__ loss_acc,
                           float* __restrict__ out) {
    if (threadIdx.x == 0) {
        float mean_sq = (*loss_acc) / (float)((size_t)N_ROWS * DIM);
        out[0] = 1.25f * mean_sq;  // q_loss + COMMITMENT_COST * e_loss
    }
}

extern "C" void kernel_launch(void* const* d_in, const int* in_sizes, int n_in,
                              void* d_out, int out_size, void* d_ws, size_t ws_size,
                              hipStream_t stream) {
    const float* x  = (const float*)d_in[0];
    const float* cb = (const float*)d_in[1];
    float* out = (float*)d_out;

    float* loss_acc = (float*)d_ws;                 // 4 B accumulator
    float* esq      = (float*)((char*)d_ws + 256);  // 512 floats

    hipMemsetAsync(d_ws, 0, 4, stream);             // zero loss accumulator
    esq_kernel<<<2, 256, 0, stream>>>(cb, esq);
    vq_kernel<<<N_ROWS / 256, 256, 0, stream>>>(x, cb, esq, out, loss_acc);
    fin_kernel<<<1, 64, 0, stream>>>(loss_acc, out);
}